// Round 2
// baseline (205.005 us; speedup 1.0000x reference)
//
#include <hip/hip_runtime.h>
#include <hip/hip_bf16.h>
#include <stdint.h>

// Problem constants
#define Bn 16
#define Ln 4096
#define KF 384   // IN_F
#define OF 384   // OUT_F

// GEMM tiling
#define BM 128
#define BN 128
#define BK 64
#define LDX 72   // padded leading dim (elements) for transposed X tile

static constexpr float kScale = 0.051031036307982884f;  // 1/sqrt(384)

typedef __attribute__((ext_vector_type(4))) float f32x4;
typedef __attribute__((ext_vector_type(2))) float f32x2;
typedef __attribute__((ext_vector_type(8))) short short8;   // 8 bf16 (4 VGPR) MFMA A/B frag
typedef __attribute__((ext_vector_type(4))) float floatx4;  // MFMA C/D frag
typedef __attribute__((ext_vector_type(4))) unsigned int uint4v;

__device__ __forceinline__ void gl_lds16(const void* g, void* l) {
  __builtin_amdgcn_global_load_lds(
      (const __attribute__((address_space(1))) unsigned int*)g,
      (__attribute__((address_space(3))) unsigned int*)l, 16, 0, 0);
}

// float -> bf16 bits, round-to-nearest-even (finite inputs only)
__device__ __forceinline__ unsigned int f2bf_bits(float f) {
  union { float f; unsigned int u; } v;
  v.f = f;
  return (v.u + 0x7FFFu + ((v.u >> 16) & 1u)) >> 16;
}
__device__ __forceinline__ unsigned int pack2bf(float lo, float hi) {
  return f2bf_bits(lo) | (f2bf_bits(hi) << 16);
}

// Kernel 1: wmod[b][o][k] = bf16( SCALE*weight[o][k]*y[b][k] * rsqrt(sum_k(.)^2 + eps) )
// One wave per (b,o) row; 4 rows per 256-thread block.
__global__ __launch_bounds__(256) void modw_kernel(const float* __restrict__ weight,
                                                   const float* __restrict__ y,
                                                   unsigned short* __restrict__ wmod) {
  int t = threadIdx.x;
  int wv = t >> 6, lane = t & 63;
  int row = blockIdx.x * 4 + wv;  // [0, Bn*OF)
  int b = row / OF, o = row % OF;
  const float* wr = weight + o * KF;
  const float* yr = y + b * KF;
  float vals[6];
  float ss = 0.f;
#pragma unroll
  for (int j = 0; j < 3; ++j) {
    int k = (lane + 64 * j) * 2;
    f32x2 wvv = *(const f32x2*)(wr + k);
    f32x2 yv = *(const f32x2*)(yr + k);
    float t0 = kScale * wvv[0] * yv[0];
    float t1 = kScale * wvv[1] * yv[1];
    vals[2 * j] = t0;
    vals[2 * j + 1] = t1;
    ss += t0 * t0 + t1 * t1;
  }
#pragma unroll
  for (int off = 32; off >= 1; off >>= 1) ss += __shfl_xor(ss, off, 64);
  float d = rsqrtf(ss + 1e-8f);
  unsigned short* orow = wmod + row * KF;
#pragma unroll
  for (int j = 0; j < 3; ++j) {
    int k = (lane + 64 * j) * 2;
    *(unsigned int*)(orow + k) = pack2bf(vals[2 * j] * d, vals[2 * j + 1] * d);
  }
}

// Kernel 2: per batch b: out[o][p] = sum_k wmod[b][o][k] * X[b][k][p]
// X[b][k][p] = Efou_flat[b*KF*Ln + k*Ln + p] (raw reshape).
// 128x128 tile per block, BK=64 chunks, 16x16x32 bf16 MFMA, 4 waves x (4x4 tiles).
__global__ __launch_bounds__(256) void gemm_kernel(const float* __restrict__ X,
                                                   const unsigned short* __restrict__ Wm,
                                                   float* __restrict__ out) {
  __shared__ unsigned short sA[BM * BK];   // [o][k], contiguous (global_load_lds layout)
  __shared__ unsigned short sX[BN * LDX];  // [p][k], padded

  // XCD swizzle: 3 consecutive logical blocks (sharing an X tile) -> same XCD
  int flat = blockIdx.x;                          // 0..1535
  int logical = (flat & 7) * 192 + (flat >> 3);   // bijection
  int mt = logical % 3;
  int nt = (logical / 3) & 31;
  int b = logical / 96;

  int t = threadIdx.x;
  int wave = t >> 6, lane = t & 63;
  int quad = lane >> 4;

  const float* Xb = X + b * (KF * Ln);
  const unsigned short* Wb = Wm + (b * OF + mt * BM) * KF;
  int pbase = nt * BN;

  floatx4 acc[4][4] = {};

  int p0 = (t & 31) * 4;     // X staging: this thread's 4 columns
  int kr0 = (t >> 5) * 8;    // and 8 k-rows
  int arow = (wave >> 1) * 64 + (lane & 15);
  int brow = (wave & 1) * 64 + (lane & 15);

  for (int kc = 0; kc < 6; ++kc) {
    int k0 = kc * BK;
    // --- stage A tile (16KB) via global_load_lds width-16 ---
#pragma unroll
    for (int j = 0; j < 4; ++j) {
      int boff = wave * 4096 + j * 1024 + lane * 16;  // byte offset in tile
      int row = boff >> 7;                            // 128B per row (64 bf16)
      int kb = (boff & 127) >> 1;
      gl_lds16(Wb + row * KF + k0 + kb, (char*)sA + boff);
    }
    // --- stage X tile: fp32 coalesced load, bf16 convert, transposed LDS write ---
    const float* xsrc = Xb + (k0 + kr0) * Ln + pbase + p0;
    f32x4 xv[8];
#pragma unroll
    for (int i = 0; i < 8; ++i) xv[i] = *(const f32x4*)(xsrc + i * Ln);
#pragma unroll
    for (int j = 0; j < 4; ++j) {
      uint4v wvec;
#pragma unroll
      for (int i = 0; i < 4; ++i)
        wvec[i] = pack2bf(xv[2 * i][j], xv[2 * i + 1][j]);
      *(uint4v*)(&sX[(p0 + j) * LDX + kr0]) = wvec;  // 16B aligned: 144*p + 16*(t>>5)
    }
    __syncthreads();
    // --- MFMA: 2 k-steps of 32, 4x4 16x16 tiles per wave ---
#pragma unroll
    for (int s = 0; s < 2; ++s) {
      int kk = s * 32 + quad * 8;
      short8 af[4], bf[4];
#pragma unroll
      for (int mi = 0; mi < 4; ++mi)
        af[mi] = *(const short8*)(&sA[(arow + mi * 16) * BK + kk]);
#pragma unroll
      for (int ni = 0; ni < 4; ++ni)
        bf[ni] = *(const short8*)(&sX[(brow + ni * 16) * LDX + kk]);
#pragma unroll
      for (int mi = 0; mi < 4; ++mi)
#pragma unroll
        for (int ni = 0; ni < 4; ++ni)
          acc[mi][ni] = __builtin_amdgcn_mfma_f32_16x16x32_bf16(af[mi], bf[ni], acc[mi][ni], 0, 0, 0);
    }
    __syncthreads();
  }

  // --- epilogue: C/D layout col=lane&15, row=quad*4+r ---
  float* outb = out + (b * OF + mt * BM) * Ln + pbase;
  int col = lane & 15;
#pragma unroll
  for (int mi = 0; mi < 4; ++mi) {
    int ob = (wave >> 1) * 64 + mi * 16 + quad * 4;
#pragma unroll
    for (int ni = 0; ni < 4; ++ni) {
      int p = (wave & 1) * 64 + ni * 16 + col;
#pragma unroll
      for (int r = 0; r < 4; ++r) outb[(ob + r) * Ln + p] = acc[mi][ni][r];
    }
  }
}

extern "C" void kernel_launch(void* const* d_in, const int* in_sizes, int n_in,
                              void* d_out, int out_size, void* d_ws, size_t ws_size,
                              hipStream_t stream) {
  const float* Efou = (const float*)d_in[0];    // [B, L, IN_F] fp32
  const float* y = (const float*)d_in[1];       // [B, IN_F] fp32
  const float* weight = (const float*)d_in[2];  // [1, OUT_F, IN_F] fp32
  float* out = (float*)d_out;                   // [B*OUT_F*L] fp32 (flat)
  unsigned short* wmod = (unsigned short*)d_ws; // [B, OUT_F, IN_F] bf16, 4.7MB

  modw_kernel<<<(Bn * OF) / 4, 256, 0, stream>>>(weight, y, wmod);
  gemm_kernel<<<Bn * (OF / BM) * (Ln / BN), 256, 0, stream>>>(Efou, wmod, out);
}

// Round 3
// 203.475 us; speedup vs baseline: 1.0075x; 1.0075x over previous
//
#include <hip/hip_runtime.h>
#include <hip/hip_bf16.h>
#include <stdint.h>

// Problem constants
#define Bn 16
#define Ln 4096
#define KF 384   // IN_F
#define OF 384   // OUT_F

// GEMM tiling
#define BM 128
#define BN 128
#define BK 64
#define LDX 72   // padded leading dim (elements) for transposed X tile

static constexpr float kScale = 0.051031036307982884f;  // 1/sqrt(384)

typedef __attribute__((ext_vector_type(4))) float f32x4;
typedef __attribute__((ext_vector_type(2))) float f32x2;
typedef __attribute__((ext_vector_type(8))) short short8;   // 8 bf16 (4 VGPR) MFMA A/B frag
typedef __attribute__((ext_vector_type(4))) float floatx4;  // MFMA C/D frag
typedef __attribute__((ext_vector_type(4))) unsigned int uint4v;

__device__ __forceinline__ void gl_lds16(const void* g, void* l) {
  __builtin_amdgcn_global_load_lds(
      (const __attribute__((address_space(1))) unsigned int*)g,
      (__attribute__((address_space(3))) unsigned int*)l, 16, 0, 0);
}

// float -> bf16 bits, round-to-nearest-even (finite inputs only)
__device__ __forceinline__ unsigned int f2bf_bits(float f) {
  union { float f; unsigned int u; } v;
  v.f = f;
  return (v.u + 0x7FFFu + ((v.u >> 16) & 1u)) >> 16;
}
__device__ __forceinline__ unsigned int pack2bf(float lo, float hi) {
  return f2bf_bits(lo) | (f2bf_bits(hi) << 16);
}

// Kernel 1: wmod[b][o][k] = bf16( SCALE*weight[o][k]*y[b][k] * rsqrt(sum_k(.)^2 + eps) )
__global__ __launch_bounds__(256) void modw_kernel(const float* __restrict__ weight,
                                                   const float* __restrict__ y,
                                                   unsigned short* __restrict__ wmod) {
  int t = threadIdx.x;
  int wv = t >> 6, lane = t & 63;
  int row = blockIdx.x * 4 + wv;  // [0, Bn*OF)
  int b = row / OF, o = row % OF;
  const float* wr = weight + o * KF;
  const float* yr = y + b * KF;
  float vals[6];
  float ss = 0.f;
#pragma unroll
  for (int j = 0; j < 3; ++j) {
    int k = (lane + 64 * j) * 2;
    f32x2 wvv = *(const f32x2*)(wr + k);
    f32x2 yv = *(const f32x2*)(yr + k);
    float t0 = kScale * wvv[0] * yv[0];
    float t1 = kScale * wvv[1] * yv[1];
    vals[2 * j] = t0;
    vals[2 * j + 1] = t1;
    ss += t0 * t0 + t1 * t1;
  }
#pragma unroll
  for (int off = 32; off >= 1; off >>= 1) ss += __shfl_xor(ss, off, 64);
  float d = rsqrtf(ss + 1e-8f);
  unsigned short* orow = wmod + row * KF;
#pragma unroll
  for (int j = 0; j < 3; ++j) {
    int k = (lane + 64 * j) * 2;
    *(unsigned int*)(orow + k) = pack2bf(vals[2 * j] * d, vals[2 * j + 1] * d);
  }
}

// Kernel 2: per batch b: out[o][p] = sum_k wmod[b][o][k] * X[b][k][p]
// Pipelined: sA double-buffered (DMA overlaps MFMA), X prefetched to VGPRs.
// Bank-conflict-free LDS via k-chunk XOR swizzles on both sA and sX.
__global__ __launch_bounds__(256, 3) void gemm_kernel(const float* __restrict__ X,
                                                      const unsigned short* __restrict__ Wm,
                                                      float* __restrict__ out) {
  __shared__ unsigned short sA[2][BM * BK];  // [o][k-chunk swizzled by o&7]
  __shared__ unsigned short sX[BN * LDX];    // [p][k-chunk swizzled by (p>>2)&7]

  // XCD swizzle: 3 consecutive logical blocks (sharing an X tile) -> same XCD
  int flat = blockIdx.x;                         // 0..1535
  int logical = (flat & 7) * 192 + (flat >> 3);  // bijection
  int mt = logical % 3;
  int nt = (logical / 3) & 31;
  int b = logical / 96;

  int t = threadIdx.x;
  int wave = t >> 6, lane = t & 63;
  int quad = lane >> 4;

  const float* Xb = X + b * (KF * Ln);
  const unsigned short* Wb = Wm + (b * OF + mt * BM) * KF;
  int pbase = nt * BN;

  floatx4 acc[4][4] = {};

  int i31 = t & 31;
  int p0 = i31 * 4;          // X staging: this thread's 4 columns
  int kr0 = (t >> 5) * 8;    // and 8 k-rows (natural)
  int kr0s = (((t >> 5) ^ (i31 & 7)) * 8);  // swizzled LDS k-offset for writes
  int arow = (wave >> 1) * 64 + (lane & 15);
  int brow = (wave & 1) * 64 + (lane & 15);
  int asw = lane & 7;                       // sA read swizzle
  int xsw = ((lane & 15) >> 2);             // sX read swizzle base (m4)

  // A staging: per-(wave,j) LDS dest is base + lane*16; source k-chunk is
  // XOR-permuted so that LDS chunk c' holds global chunk c'^(row&7).
  int aoff[4], asrc_row[4], asrc_c[4];
#pragma unroll
  for (int j = 0; j < 4; ++j) {
    int boff = wave * 4096 + j * 1024 + lane * 16;  // byte offset in 16KB tile
    int row = boff >> 7;                            // 128B per row (64 bf16)
    int cp = (boff >> 4) & 7;                       // LDS chunk slot
    aoff[j] = boff;
    asrc_row[j] = row;
    asrc_c[j] = (cp ^ (row & 7)) * 8;               // global k-element offset
  }

  f32x4 xv[8];
  unsigned int wv4[4][4];

  // ---- prologue: stage A(0), load+convert+write X(0) ----
#pragma unroll
  for (int j = 0; j < 4; ++j)
    gl_lds16(Wb + asrc_row[j] * KF + 0 + asrc_c[j], (char*)sA[0] + aoff[j]);
  {
    const float* xsrc = Xb + (0 + kr0) * Ln + pbase + p0;
#pragma unroll
    for (int i = 0; i < 8; ++i) xv[i] = *(const f32x4*)(xsrc + i * Ln);
#pragma unroll
    for (int j = 0; j < 4; ++j)
#pragma unroll
      for (int i = 0; i < 4; ++i)
        wv4[j][i] = pack2bf(xv[2 * i][j], xv[2 * i + 1][j]);
#pragma unroll
    for (int j = 0; j < 4; ++j)
      *(uint4v*)(&sX[(p0 + j) * LDX + kr0s]) = *(uint4v*)wv4[j];
  }
  __syncthreads();  // drains A DMA (vmcnt) + publishes sX

#pragma unroll
  for (int kc = 0; kc < 6; ++kc) {
    int cur = kc & 1;
    // ---- prefetch next chunk (A via DMA to other buffer, X to VGPRs) ----
    if (kc < 5) {
      int k0n = (kc + 1) * BK;
#pragma unroll
      for (int j = 0; j < 4; ++j)
        gl_lds16(Wb + asrc_row[j] * KF + k0n + asrc_c[j], (char*)sA[cur ^ 1] + aoff[j]);
      const float* xsrc = Xb + (k0n + kr0) * Ln + pbase + p0;
#pragma unroll
      for (int i = 0; i < 8; ++i) xv[i] = *(const f32x4*)(xsrc + i * Ln);
    }
    // ---- MFMA on current chunk ----
#pragma unroll
    for (int s = 0; s < 2; ++s) {
      short8 af[4], bf[4];
#pragma unroll
      for (int mi = 0; mi < 4; ++mi) {
        int ca = (((s << 2) | quad) ^ asw) * 8;
        af[mi] = *(const short8*)(&sA[cur][(arow + mi * 16) * BK + ca]);
      }
#pragma unroll
      for (int ni = 0; ni < 4; ++ni) {
        int cx = (((s << 2) | quad) ^ (((ni & 1) << 2) | xsw)) * 8;
        bf[ni] = *(const short8*)(&sX[(brow + ni * 16) * LDX + cx]);
      }
#pragma unroll
      for (int mi = 0; mi < 4; ++mi)
#pragma unroll
        for (int ni = 0; ni < 4; ++ni)
          acc[mi][ni] = __builtin_amdgcn_mfma_f32_16x16x32_bf16(af[mi], bf[ni], acc[mi][ni], 0, 0, 0);
    }
    // ---- convert in MFMA shadow, then publish sX for next chunk ----
    if (kc < 5) {
#pragma unroll
      for (int j = 0; j < 4; ++j)
#pragma unroll
        for (int i = 0; i < 4; ++i)
          wv4[j][i] = pack2bf(xv[2 * i][j], xv[2 * i + 1][j]);
      __syncthreads();  // all waves done reading sX (and drains next-A DMA)
#pragma unroll
      for (int j = 0; j < 4; ++j)
        *(uint4v*)(&sX[(p0 + j) * LDX + kr0s]) = *(uint4v*)wv4[j];
      __syncthreads();  // sX(kc+1) visible
    }
  }

  // --- epilogue: C/D layout col=lane&15, row=quad*4+r ---
  float* outb = out + (b * OF + mt * BM) * Ln + pbase;
  int col = lane & 15;
#pragma unroll
  for (int mi = 0; mi < 4; ++mi) {
    int ob = (wave >> 1) * 64 + mi * 16 + quad * 4;
#pragma unroll
    for (int ni = 0; ni < 4; ++ni) {
      int p = (wave & 1) * 64 + ni * 16 + col;
#pragma unroll
      for (int r = 0; r < 4; ++r) outb[(ob + r) * Ln + p] = acc[mi][ni][r];
    }
  }
}

extern "C" void kernel_launch(void* const* d_in, const int* in_sizes, int n_in,
                              void* d_out, int out_size, void* d_ws, size_t ws_size,
                              hipStream_t stream) {
  const float* Efou = (const float*)d_in[0];    // [B, L, IN_F] fp32
  const float* y = (const float*)d_in[1];       // [B, IN_F] fp32
  const float* weight = (const float*)d_in[2];  // [1, OUT_F, IN_F] fp32
  float* out = (float*)d_out;                   // [B*OUT_F*L] fp32 (flat)
  unsigned short* wmod = (unsigned short*)d_ws; // [B, OUT_F, IN_F] bf16, 4.7MB

  modw_kernel<<<(Bn * OF) / 4, 256, 0, stream>>>(weight, y, wmod);
  gemm_kernel<<<Bn * (OF / BM) * (Ln / BN), 256, 0, stream>>>(Efou, wmod, out);
}